// Round 1
// baseline (623.701 us; speedup 1.0000x reference)
//
#include <hip/hip_runtime.h>

// MultiAttention: B=32768, HOP=32, D=64.
// score[b,h] = sum_d tanh((rel[b,h]@w_r)[d])*va[64+d] + tanh((nbr[b,h]@w_t)[d])*va[128+d]
// out = softmax over h. (entity/w_h dead: head branch is tanh(0)=0.)
//
// v2 vs v1 (181us/dispatch, VALUBusy 37%, MfmaUtil 11.5%, Occ ~21%):
//  Theory: v1 kept 32 bf16x8 W frags (128 regs) in the unified RF
//  (124 arch VGPR + ~128 acc) -> 2 waves/SIMD, latency-bound.
//  (1) W frags pre-swizzled into LDS (32KB, one ds_read_b128/frag) ->
//      ~128 fewer regs, __launch_bounds__(256,3) -> 3 waves/SIMD.
//  (2) Software pipeline: nbr loads issue before rel compute; next
//      batch's rel loads issue before nbr compute.
//  (3) tanh = 1 - 2*rcp(exp2(x*2log2e)+1): 5 ops, clamp-free.
//  (4) split packs bf16 pairs with v_perm_b32.

typedef short bf16x8 __attribute__((ext_vector_type(8)));
typedef float f32x4 __attribute__((ext_vector_type(4)));
typedef unsigned int u32x4 __attribute__((ext_vector_type(4)));

#define NB   32768
#define NHOP 32
#define ND   64
#define NBLK 2048
#define NWAVES (NBLK * 4)

__device__ __forceinline__ float tanh_cheap(float x) {
  // tanh(x) = 1 - 2/(e^{2x}+1); exp2f -> v_exp_f32. x=+big -> rcp(inf)=0 -> 1;
  // x=-big -> rcp(1)=1 -> -1. No clamp, no NaN path.
  float e2 = exp2f(x * 2.885390081777927f);
  return fmaf(-2.f, __builtin_amdgcn_rcpf(e2 + 1.f), 1.f);
}

// split 8 fp32 (two float4, consecutive k) into bf16 hi (truncate) + lo (residual)
__device__ __forceinline__ void split2(float4 v0, float4 v1, bf16x8 &hi, bf16x8 &lo) {
  float xs[8] = {v0.x, v0.y, v0.z, v0.w, v1.x, v1.y, v1.z, v1.w};
  u32x4 hw, lw;
#pragma unroll
  for (int p = 0; p < 4; ++p) {
    unsigned ub = __builtin_bit_cast(unsigned, xs[2 * p]);
    unsigned ua = __builtin_bit_cast(unsigned, xs[2 * p + 1]);
    hw[p] = __builtin_amdgcn_perm(ua, ub, 0x07060302u);  // (hi16(ua)<<16)|hi16(ub)
    float hb = __builtin_bit_cast(float, ub & 0xffff0000u);
    float ha = __builtin_bit_cast(float, ua & 0xffff0000u);
    unsigned lb = __builtin_bit_cast(unsigned, xs[2 * p] - hb);
    unsigned la = __builtin_bit_cast(unsigned, xs[2 * p + 1] - ha);
    lw[p] = __builtin_amdgcn_perm(la, lb, 0x07060302u);
  }
  hi = __builtin_bit_cast(bf16x8, hw);
  lo = __builtin_bit_cast(bf16x8, lw);
}

__global__ __launch_bounds__(256, 3)
void attn_fused(const float* __restrict__ rel, const float* __restrict__ nbr,
                const float* __restrict__ wr, const float* __restrict__ wt,
                const float* __restrict__ va, float* __restrict__ out) {
  // [slot][lane]: slot = ((mat*2+c)*4+nt)*2+half; 32 slots x 64 lanes x 16B = 32KB
  __shared__ bf16x8 wsl[32][64];

  const int lane  = threadIdx.x & 63;
  const int wslot = threadIdx.x >> 6;
  const int wid   = (int)blockIdx.x * 4 + wslot;
  const int l15   = lane & 15;   // A row m / C col / B col n
  const int lg    = lane >> 4;   // k-chunk group / C row group

  float va1[4], va2[4];
#pragma unroll
  for (int nt = 0; nt < 4; ++nt) {
    va1[nt] = va[64 + nt * 16 + l15];
    va2[nt] = va[128 + nt * 16 + l15];
  }

#define LOADM(DST, SRC, B) do {                                           \
    const float* _p0 = (SRC) + ((size_t)(B) * NHOP + l15) * ND + lg * 8;  \
    DST[0][0] = *(const float4*)(_p0);                                    \
    DST[0][1] = *(const float4*)(_p0 + 4);                                \
    DST[0][2] = *(const float4*)(_p0 + 32);                               \
    DST[0][3] = *(const float4*)(_p0 + 36);                               \
    const float* _p1 = _p0 + 16 * ND;                                     \
    DST[1][0] = *(const float4*)(_p1);                                    \
    DST[1][1] = *(const float4*)(_p1 + 4);                                \
    DST[1][2] = *(const float4*)(_p1 + 32);                               \
    DST[1][3] = *(const float4*)(_p1 + 36);                               \
  } while (0)

  // prologue rel loads issued before W staging so they overlap it
  float4 R[2][4];
  LOADM(R, rel, wid);

  // one-time W staging: 4 (mat,c,nt) combos per wave, hi+lo slots each
#pragma unroll
  for (int q = 0; q < 4; ++q) {
    const int combo = wslot * 4 + q;              // (mat*2+c)*4+nt
    const int mat = combo >> 3, c = (combo >> 2) & 1, nt = combo & 3;
    const float* W = mat ? wt : wr;
    u32x4 hw, lw;
#pragma unroll
    for (int p = 0; p < 4; ++p) {
      float x0 = W[(c * 32 + lg * 8 + 2 * p) * 64 + nt * 16 + l15];
      float x1 = W[(c * 32 + lg * 8 + 2 * p + 1) * 64 + nt * 16 + l15];
      unsigned ub = __builtin_bit_cast(unsigned, x0);
      unsigned ua = __builtin_bit_cast(unsigned, x1);
      hw[p] = __builtin_amdgcn_perm(ua, ub, 0x07060302u);
      float hb = __builtin_bit_cast(float, ub & 0xffff0000u);
      float ha = __builtin_bit_cast(float, ua & 0xffff0000u);
      unsigned lb = __builtin_bit_cast(unsigned, x0 - hb);
      unsigned la = __builtin_bit_cast(unsigned, x1 - ha);
      lw[p] = __builtin_amdgcn_perm(la, lb, 0x07060302u);
    }
    wsl[combo * 2 + 0][lane] = __builtin_bit_cast(bf16x8, hw);
    wsl[combo * 2 + 1][lane] = __builtin_bit_cast(bf16x8, lw);
  }
  __syncthreads();

#define COMPUTE_MAT(BUF, MATB, VAV) do {                                        \
    bf16x8 ahi[2][2], alo[2][2];                                                \
    _Pragma("unroll")                                                           \
    for (int tt = 0; tt < 2; ++tt) {                                            \
      split2(BUF[tt][0], BUF[tt][1], ahi[tt][0], alo[tt][0]);                   \
      split2(BUF[tt][2], BUF[tt][3], ahi[tt][1], alo[tt][1]);                   \
    }                                                                           \
    f32x4 acc[2][4];                                                            \
    _Pragma("unroll")                                                           \
    for (int tt = 0; tt < 2; ++tt)                                              \
      _Pragma("unroll")                                                         \
      for (int nt = 0; nt < 4; ++nt) acc[tt][nt] = (f32x4){0.f, 0.f, 0.f, 0.f}; \
    _Pragma("unroll")                                                           \
    for (int c = 0; c < 2; ++c)                                                 \
      _Pragma("unroll")                                                         \
      for (int nt = 0; nt < 4; ++nt) {                                          \
        bf16x8 wh = wsl[((MATB) + c) * 8 + nt * 2 + 0][lane];                   \
        bf16x8 wl = wsl[((MATB) + c) * 8 + nt * 2 + 1][lane];                   \
        _Pragma("unroll")                                                       \
        for (int tt = 0; tt < 2; ++tt) {                                        \
          acc[tt][nt] = __builtin_amdgcn_mfma_f32_16x16x32_bf16(ahi[tt][c], wh, acc[tt][nt], 0, 0, 0); \
          acc[tt][nt] = __builtin_amdgcn_mfma_f32_16x16x32_bf16(alo[tt][c], wh, acc[tt][nt], 0, 0, 0); \
          acc[tt][nt] = __builtin_amdgcn_mfma_f32_16x16x32_bf16(ahi[tt][c], wl, acc[tt][nt], 0, 0, 0); \
        }                                                                       \
      }                                                                         \
    _Pragma("unroll")                                                           \
    for (int tt = 0; tt < 2; ++tt)                                              \
      _Pragma("unroll")                                                         \
      for (int nt = 0; nt < 4; ++nt)                                            \
        _Pragma("unroll")                                                       \
        for (int rr = 0; rr < 4; ++rr)                                          \
          sc[tt][rr] = fmaf(tanh_cheap(acc[tt][nt][rr]), VAV[nt], sc[tt][rr]);  \
  } while (0)

  for (int b = wid; b < NB; b += NWAVES) {
    float4 Nb[2][4];
    LOADM(Nb, nbr, b);            // in flight during rel compute

    float sc[2][4] = {{0.f, 0.f, 0.f, 0.f}, {0.f, 0.f, 0.f, 0.f}};

    COMPUTE_MAT(R, 0, va1);       // rel @ w_r (slots 0..15)

    const int bn = b + NWAVES;
    if (bn < NB) LOADM(R, rel, bn);  // prefetch next rel under nbr compute

    COMPUTE_MAT(Nb, 2, va2);      // nbr @ w_t (slots 16..31)

    // column reduction: sum over the 16 lanes sharing a C-row group
#pragma unroll
    for (int m = 1; m <= 8; m <<= 1)
#pragma unroll
      for (int tt = 0; tt < 2; ++tt)
#pragma unroll
        for (int rr = 0; rr < 4; ++rr)
          sc[tt][rr] += __shfl_xor(sc[tt][rr], m, 64);

    // softmax over the 32 hops
    float smax = fmaxf(fmaxf(sc[0][0], sc[0][1]), fmaxf(sc[0][2], sc[0][3]));
    smax = fmaxf(smax, fmaxf(fmaxf(sc[1][0], sc[1][1]), fmaxf(sc[1][2], sc[1][3])));
    smax = fmaxf(smax, __shfl_xor(smax, 16, 64));
    smax = fmaxf(smax, __shfl_xor(smax, 32, 64));

    float e[2][4];
    float ssum = 0.f;
#pragma unroll
    for (int tt = 0; tt < 2; ++tt)
#pragma unroll
      for (int rr = 0; rr < 4; ++rr) {
        e[tt][rr] = __expf(sc[tt][rr] - smax);
        ssum += e[tt][rr];
      }
    ssum += __shfl_xor(ssum, 16, 64);
    ssum += __shfl_xor(ssum, 32, 64);
    float inv = __builtin_amdgcn_rcpf(ssum);

    if (l15 == 0) {  // one writer lane per group; rows lg*4+rr contiguous -> float4
      float* ob = out + (size_t)b * NHOP;
      float4 o0 = {e[0][0] * inv, e[0][1] * inv, e[0][2] * inv, e[0][3] * inv};
      float4 o1 = {e[1][0] * inv, e[1][1] * inv, e[1][2] * inv, e[1][3] * inv};
      *(float4*)(ob + lg * 4)      = o0;
      *(float4*)(ob + 16 + lg * 4) = o1;
    }
  }
}

extern "C" void kernel_launch(void* const* d_in, const int* in_sizes, int n_in,
                              void* d_out, int out_size, void* d_ws, size_t ws_size,
                              hipStream_t stream) {
  // inputs: 0 entity (dead), 1 relation, 2 neighbor, 3 w_h (dead), 4 w_t, 5 w_r, 6 v_a
  const float* rel = (const float*)d_in[1];
  const float* nbr = (const float*)d_in[2];
  const float* wt  = (const float*)d_in[4];
  const float* wr  = (const float*)d_in[5];
  const float* va  = (const float*)d_in[6];
  float* out = (float*)d_out;

  attn_fused<<<NBLK, 256, 0, stream>>>(rel, nbr, wr, wt, va, out);
}

// Round 2
// 613.700 us; speedup vs baseline: 1.0163x; 1.0163x over previous
//
#include <hip/hip_runtime.h>

// MultiAttention: B=32768, HOP=32, D=64.
// score[b,h] = sum_d tanh((rel[b,h]@w_r)[d])*va[64+d] + tanh((nbr[b,h]@w_t)[d])*va[128+d]
// out = softmax over h. (entity/w_h dead: head branch is tanh(0)=0.)
//
// v3 vs v2 (267us/dispatch, WRITE_SIZE 200MB = scratch spill disaster):
//  v2's (256,3) cap (168 regs) vs ~150+ live values -> compiler spilled
//  ~12 dwords/lane/iter to scratch (196MB writes + re-reads via HBM).
//  Fix: drain accumulators per n-tile PAIR (acc 32->16 regs). Peak live
//  ~115 regs, well under the 168 cap -> no spill, keep 3 waves/SIMD.
//  Keep: LDS weight bank (32KB), Nb-under-rel + nextR-under-nbr rotation,
//  cheap tanh, v_perm bf16 packing.

typedef short bf16x8 __attribute__((ext_vector_type(8)));
typedef float f32x4 __attribute__((ext_vector_type(4)));
typedef unsigned int u32x4 __attribute__((ext_vector_type(4)));

#define NB   32768
#define NHOP 32
#define ND   64
#define NBLK 2048
#define NWAVES (NBLK * 4)

__device__ __forceinline__ float tanh_cheap(float x) {
  // tanh(x) = 1 - 2/(e^{2x}+1); exp2f -> v_exp_f32. x=+big -> rcp(inf)=0 -> 1;
  // x=-big -> rcp(1)=1 -> -1. No clamp, no NaN path.
  float e2 = exp2f(x * 2.885390081777927f);
  return fmaf(-2.f, __builtin_amdgcn_rcpf(e2 + 1.f), 1.f);
}

// split 8 fp32 (two float4, consecutive k) into bf16 hi (truncate) + lo (residual)
__device__ __forceinline__ void split2(float4 v0, float4 v1, bf16x8 &hi, bf16x8 &lo) {
  float xs[8] = {v0.x, v0.y, v0.z, v0.w, v1.x, v1.y, v1.z, v1.w};
  u32x4 hw, lw;
#pragma unroll
  for (int p = 0; p < 4; ++p) {
    unsigned ub = __builtin_bit_cast(unsigned, xs[2 * p]);
    unsigned ua = __builtin_bit_cast(unsigned, xs[2 * p + 1]);
    hw[p] = __builtin_amdgcn_perm(ua, ub, 0x07060302u);  // (hi16(ua)<<16)|hi16(ub)
    float hb = __builtin_bit_cast(float, ub & 0xffff0000u);
    float ha = __builtin_bit_cast(float, ua & 0xffff0000u);
    unsigned lb = __builtin_bit_cast(unsigned, xs[2 * p] - hb);
    unsigned la = __builtin_bit_cast(unsigned, xs[2 * p + 1] - ha);
    lw[p] = __builtin_amdgcn_perm(la, lb, 0x07060302u);
  }
  hi = __builtin_bit_cast(bf16x8, hw);
  lo = __builtin_bit_cast(bf16x8, lw);
}

__global__ __launch_bounds__(256, 3)
void attn_fused(const float* __restrict__ rel, const float* __restrict__ nbr,
                const float* __restrict__ wr, const float* __restrict__ wt,
                const float* __restrict__ va, float* __restrict__ out) {
  // [slot][lane]: slot = ((mat*2+c)*4+nt)*2+half; 32 slots x 64 lanes x 16B = 32KB
  __shared__ bf16x8 wsl[32][64];

  const int lane  = threadIdx.x & 63;
  const int wslot = threadIdx.x >> 6;
  const int wid   = (int)blockIdx.x * 4 + wslot;
  const int l15   = lane & 15;   // A row m / C col / B col n
  const int lg    = lane >> 4;   // k-chunk group / C row group

  float va1[4], va2[4];
#pragma unroll
  for (int nt = 0; nt < 4; ++nt) {
    va1[nt] = va[64 + nt * 16 + l15];
    va2[nt] = va[128 + nt * 16 + l15];
  }

#define LOADM(DST, SRC, B) do {                                           \
    const float* _p0 = (SRC) + ((size_t)(B) * NHOP + l15) * ND + lg * 8;  \
    DST[0][0] = *(const float4*)(_p0);                                    \
    DST[0][1] = *(const float4*)(_p0 + 4);                                \
    DST[0][2] = *(const float4*)(_p0 + 32);                               \
    DST[0][3] = *(const float4*)(_p0 + 36);                               \
    const float* _p1 = _p0 + 16 * ND;                                     \
    DST[1][0] = *(const float4*)(_p1);                                    \
    DST[1][1] = *(const float4*)(_p1 + 4);                                \
    DST[1][2] = *(const float4*)(_p1 + 32);                               \
    DST[1][3] = *(const float4*)(_p1 + 36);                               \
  } while (0)

  // prologue rel loads issued before W staging so they overlap it
  float4 R[2][4];
  LOADM(R, rel, wid);

  // one-time W staging: 4 (mat,c,nt) combos per wave, hi+lo slots each
#pragma unroll
  for (int q = 0; q < 4; ++q) {
    const int combo = wslot * 4 + q;              // (mat*2+c)*4+nt
    const int mat = combo >> 3, c = (combo >> 2) & 1, nt = combo & 3;
    const float* W = mat ? wt : wr;
    u32x4 hw, lw;
#pragma unroll
    for (int p = 0; p < 4; ++p) {
      float x0 = W[(c * 32 + lg * 8 + 2 * p) * 64 + nt * 16 + l15];
      float x1 = W[(c * 32 + lg * 8 + 2 * p + 1) * 64 + nt * 16 + l15];
      unsigned ub = __builtin_bit_cast(unsigned, x0);
      unsigned ua = __builtin_bit_cast(unsigned, x1);
      hw[p] = __builtin_amdgcn_perm(ua, ub, 0x07060302u);
      float hb = __builtin_bit_cast(float, ub & 0xffff0000u);
      float ha = __builtin_bit_cast(float, ua & 0xffff0000u);
      unsigned lb = __builtin_bit_cast(unsigned, x0 - hb);
      unsigned la = __builtin_bit_cast(unsigned, x1 - ha);
      lw[p] = __builtin_amdgcn_perm(la, lb, 0x07060302u);
    }
    wsl[combo * 2 + 0][lane] = __builtin_bit_cast(bf16x8, hw);
    wsl[combo * 2 + 1][lane] = __builtin_bit_cast(bf16x8, lw);
  }
  __syncthreads();

  // Split input buffer into bf16 hi/lo A-fragments (frees the fp32 buffer).
#define SPLIT_BUF(BUF, AHI, ALO) do {                                     \
    _Pragma("unroll")                                                     \
    for (int tt = 0; tt < 2; ++tt) {                                      \
      split2(BUF[tt][0], BUF[tt][1], AHI[tt][0], ALO[tt][0]);             \
      split2(BUF[tt][2], BUF[tt][3], AHI[tt][1], ALO[tt][1]);             \
    }                                                                     \
  } while (0)

  // n-tiles processed in PAIRS: only 16 acc regs live at a time; each
  // pair's tanh/fma drain overlaps the next pair's MFMA chain.
#define COMPUTE_MAT(AHI, ALO, MATB, VAV) do {                                   \
    _Pragma("unroll")                                                           \
    for (int np = 0; np < 2; ++np) {                                            \
      f32x4 acc[2][2];                                                          \
      _Pragma("unroll")                                                         \
      for (int ntl = 0; ntl < 2; ++ntl)                                         \
        _Pragma("unroll")                                                       \
        for (int tt = 0; tt < 2; ++tt) acc[ntl][tt] = (f32x4){0.f,0.f,0.f,0.f}; \
      _Pragma("unroll")                                                         \
      for (int ntl = 0; ntl < 2; ++ntl) {                                       \
        const int nt = np * 2 + ntl;                                            \
        _Pragma("unroll")                                                       \
        for (int c = 0; c < 2; ++c) {                                           \
          bf16x8 wh = wsl[((MATB) + c) * 8 + nt * 2 + 0][lane];                 \
          bf16x8 wl = wsl[((MATB) + c) * 8 + nt * 2 + 1][lane];                 \
          _Pragma("unroll")                                                     \
          for (int tt = 0; tt < 2; ++tt) {                                      \
            acc[ntl][tt] = __builtin_amdgcn_mfma_f32_16x16x32_bf16(AHI[tt][c], wh, acc[ntl][tt], 0, 0, 0); \
            acc[ntl][tt] = __builtin_amdgcn_mfma_f32_16x16x32_bf16(ALO[tt][c], wh, acc[ntl][tt], 0, 0, 0); \
            acc[ntl][tt] = __builtin_amdgcn_mfma_f32_16x16x32_bf16(AHI[tt][c], wl, acc[ntl][tt], 0, 0, 0); \
          }                                                                     \
        }                                                                       \
      }                                                                         \
      _Pragma("unroll")                                                         \
      for (int ntl = 0; ntl < 2; ++ntl)                                         \
        _Pragma("unroll")                                                       \
        for (int tt = 0; tt < 2; ++tt)                                          \
          _Pragma("unroll")                                                     \
          for (int rr = 0; rr < 4; ++rr)                                        \
            sc[tt][rr] = fmaf(tanh_cheap(acc[ntl][tt][rr]), VAV[np * 2 + ntl], sc[tt][rr]); \
    }                                                                           \
  } while (0)

  for (int b = wid; b < NB; b += NWAVES) {
    float4 Nb[2][4];
    LOADM(Nb, nbr, b);            // in flight during rel compute

    float sc[2][4] = {{0.f, 0.f, 0.f, 0.f}, {0.f, 0.f, 0.f, 0.f}};

    {
      bf16x8 ahi[2][2], alo[2][2];
      SPLIT_BUF(R, ahi, alo);     // R fp32 dead after this
      COMPUTE_MAT(ahi, alo, 0, va1);   // rel @ w_r (slots 0..15)
    }

    const int bn = b + NWAVES;
    if (bn < NB) LOADM(R, rel, bn);  // prefetch next rel under nbr compute

    {
      bf16x8 ahi[2][2], alo[2][2];
      SPLIT_BUF(Nb, ahi, alo);    // Nb fp32 dead after this
      COMPUTE_MAT(ahi, alo, 2, va2);   // nbr @ w_t (slots 16..31)
    }

    // column reduction: sum over the 16 lanes sharing a C-row group
#pragma unroll
    for (int m = 1; m <= 8; m <<= 1)
#pragma unroll
      for (int tt = 0; tt < 2; ++tt)
#pragma unroll
        for (int rr = 0; rr < 4; ++rr)
          sc[tt][rr] += __shfl_xor(sc[tt][rr], m, 64);

    // softmax over the 32 hops
    float smax = fmaxf(fmaxf(sc[0][0], sc[0][1]), fmaxf(sc[0][2], sc[0][3]));
    smax = fmaxf(smax, fmaxf(fmaxf(sc[1][0], sc[1][1]), fmaxf(sc[1][2], sc[1][3])));
    smax = fmaxf(smax, __shfl_xor(smax, 16, 64));
    smax = fmaxf(smax, __shfl_xor(smax, 32, 64));

    float e[2][4];
    float ssum = 0.f;
#pragma unroll
    for (int tt = 0; tt < 2; ++tt)
#pragma unroll
      for (int rr = 0; rr < 4; ++rr) {
        e[tt][rr] = __expf(sc[tt][rr] - smax);
        ssum += e[tt][rr];
      }
    ssum += __shfl_xor(ssum, 16, 64);
    ssum += __shfl_xor(ssum, 32, 64);
    float inv = __builtin_amdgcn_rcpf(ssum);

    if (l15 == 0) {  // one writer lane per group; rows lg*4+rr contiguous -> float4
      float* ob = out + (size_t)b * NHOP;
      float4 o0 = {e[0][0] * inv, e[0][1] * inv, e[0][2] * inv, e[0][3] * inv};
      float4 o1 = {e[1][0] * inv, e[1][1] * inv, e[1][2] * inv, e[1][3] * inv};
      *(float4*)(ob + lg * 4)      = o0;
      *(float4*)(ob + 16 + lg * 4) = o1;
    }
  }
}

extern "C" void kernel_launch(void* const* d_in, const int* in_sizes, int n_in,
                              void* d_out, int out_size, void* d_ws, size_t ws_size,
                              hipStream_t stream) {
  // inputs: 0 entity (dead), 1 relation, 2 neighbor, 3 w_h (dead), 4 w_t, 5 w_r, 6 v_a
  const float* rel = (const float*)d_in[1];
  const float* nbr = (const float*)d_in[2];
  const float* wt  = (const float*)d_in[4];
  const float* wr  = (const float*)d_in[5];
  const float* va  = (const float*)d_in[6];
  float* out = (float*)d_out;

  attn_fused<<<NBLK, 256, 0, stream>>>(rel, nbr, wr, wt, va, out);
}